// Round 20
// baseline (73.089 us; speedup 1.0000x reference)
//
#include <hip/hip_runtime.h>
#include <hip/hip_bf16.h>
#include <math.h>

#define NN 8192
#define DD 128
#define BM 256        // rows per block (4 waves x 64)
#define BN 64         // cols per j-tile
#define NPART 16      // grid = 32*16 = 512 blocks (2 blocks/CU, single batch)
#define JRANGE (NN / NPART)    // 512
#define NTILES (JRANGE / BN)   // 8
#define NBLKS ((NN / BM) * NPART)   // 512

typedef __attribute__((ext_vector_type(8))) short bf16x8;
typedef __attribute__((ext_vector_type(4))) float f32x4;

// ws byte offsets
#define WS_SJC 0                          // 8192 * float2 = 64 KB
#define WS_HPK 65536                      // 32 KB (uint keys)
#define WS_HNK (WS_HPK + NN * 4)          // 32 KB
#define WS_CNT (WS_HNK + NN * 4)          // 256 B (ticket)
#define WS_AB  (WS_CNT + 256)             // 2 MB (bf16, fragment-contiguous)

__device__ __forceinline__ unsigned fkey(float f) {
    unsigned u = __float_as_uint(f);
    return (u & 0x80000000u) ? ~u : (u | 0x80000000u);
}
__device__ __forceinline__ float fkey_inv(unsigned k) {
    unsigned u = (k & 0x80000000u) ? (k ^ 0x80000000u) : ~k;
    return __uint_as_float(u);
}
__device__ __forceinline__ ushort f2bf(float x) {
    __hip_bfloat16 h = __float2bfloat16(x);
    return *reinterpret_cast<ushort*>(&h);
}

// fused: fp32 sqnorm + bf16 convert (fragment-contiguous) + metadata + key/ticket init
// bf16 ushort index(row,k) = (row>>4)*2048 + (k>>5)*512 + ((k>>3)&3)*128
//                          + (row&15)*8 + (k&7)
__global__ __launch_bounds__(256)
void prepq_k(const float* __restrict__ emb, const int* __restrict__ lab,
             float2* __restrict__ sjc, unsigned* __restrict__ hpK,
             unsigned* __restrict__ hnK, unsigned* __restrict__ ticket,
             ushort* __restrict__ aB) {
    const int lane = threadIdx.x & 63;
    const int w    = threadIdx.x >> 6;
    const int half = lane >> 5;
    const int l32  = lane & 31;
    const int row  = blockIdx.x * 8 + w * 2 + half;

    float4 v = reinterpret_cast<const float4*>(emb)[row * 32 + l32];
    float s = 0.f;
    s = fmaf(v.x, v.x, s); s = fmaf(v.y, v.y, s);
    s = fmaf(v.z, v.z, s); s = fmaf(v.w, v.w, s);
#pragma unroll
    for (int off = 1; off < 32; off <<= 1) s += __shfl_xor(s, off, 64);

    ushort4 b;
    b.x = f2bf(v.x); b.y = f2bf(v.y); b.z = f2bf(v.z); b.w = f2bf(v.w);
    const int idx = (row >> 4) * 2048 + (l32 >> 3) * 512 + ((l32 >> 1) & 3) * 128
                  + (row & 15) * 8 + (l32 & 1) * 4;
    *reinterpret_cast<ushort4*>(aB + idx) = b;

    if (l32 == 0) sjc[row] = make_float2(s, __int_as_float(lab[row]));
    if (threadIdx.x < 8) {
        int r0 = blockIdx.x * 8 + threadIdx.x;
        hpK[r0] = 0x007FFFFFu;   // fkey(-inf)
        hnK[r0] = 0xFF800000u;   // fkey(+inf)
    }
    if (blockIdx.x == 0 && threadIdx.x == 0) ticket[0] = 0;   // reset every call
}

__global__ __launch_bounds__(256, 2)
void hardest_k(const ushort* __restrict__ aB, const float2* __restrict__ sjc,
               unsigned* __restrict__ hpK, unsigned* __restrict__ hnK,
               unsigned* __restrict__ ticket, float* __restrict__ out) {
    const int tid  = threadIdx.x;
    const int w    = tid >> 6;
    const int lane = tid & 63;
    const int lrow = lane & 15;
    const int lk   = lane >> 4;
    const int ib   = (int)blockIdx.x >> 4;    // 0..31
    const int part = (int)blockIdx.x & 15;    // 0..15
    const int i0   = ib * BM;
    const int jbeg = part * JRANGE;

    // persistent A fragments: 4 strips of 16 rows x 4 k-chunks (64 VGPR)
    bf16x8 a[4][4];
#pragma unroll
    for (int s = 0; s < 4; ++s) {
        const int gA = ib * 16 + w * 4 + s;
#pragma unroll
        for (int q = 0; q < 4; ++q)
            a[s][q] = *reinterpret_cast<const bf16x8*>(&aB[gA * 2048 + q * 512 + lane * 8]);
    }
    int   li[4][4];
    float hpg[4][4], hng[4][4];
#pragma unroll
    for (int s = 0; s < 4; ++s)
#pragma unroll
        for (int t = 0; t < 4; ++t) {
            float2 md = sjc[i0 + w * 64 + s * 16 + lk * 4 + t];
            li[s][t]  = __float_as_int(md.y);
            hpg[s][t] = -INFINITY;
            hng[s][t] =  INFINITY;
        }

#pragma unroll 2
    for (int jt = 0; jt < NTILES; ++jt) {
        const int j0 = jbeg + jt * BN;
#pragma unroll
        for (int c = 0; c < 4; ++c) {
            const int gB = (j0 >> 4) + c;
            const ushort* bp = &aB[gB * 2048 + lane * 8];
            bf16x8 b0 = *reinterpret_cast<const bf16x8*>(bp);
            bf16x8 b1 = *reinterpret_cast<const bf16x8*>(bp + 512);
            bf16x8 b2 = *reinterpret_cast<const bf16x8*>(bp + 1024);
            bf16x8 b3 = *reinterpret_cast<const bf16x8*>(bp + 1536);
            float2 sv = sjc[j0 + c * 16 + lrow];
            f32x4 acc[4];
            f32x4 zero = {0.f, 0.f, 0.f, 0.f};
#pragma unroll
            for (int s = 0; s < 4; ++s) acc[s] = zero;
            __builtin_amdgcn_s_setprio(1);
#pragma unroll
            for (int s = 0; s < 4; ++s) {
                acc[s] = __builtin_amdgcn_mfma_f32_16x16x32_bf16(a[s][0], b0, acc[s], 0, 0, 0);
                acc[s] = __builtin_amdgcn_mfma_f32_16x16x32_bf16(a[s][1], b1, acc[s], 0, 0, 0);
                acc[s] = __builtin_amdgcn_mfma_f32_16x16x32_bf16(a[s][2], b2, acc[s], 0, 0, 0);
                acc[s] = __builtin_amdgcn_mfma_f32_16x16x32_bf16(a[s][3], b3, acc[s], 0, 0, 0);
            }
            __builtin_amdgcn_s_setprio(0);
            const float sqj = sv.x;
            const int   lj  = __float_as_int(sv.y);
#pragma unroll
            for (int s = 0; s < 4; ++s)
#pragma unroll
                for (int t = 0; t < 4; ++t) {
                    float gg = fmaf(-2.f, acc[s][t], sqj);        // g = sqj - 2*dot
                    bool same = (li[s][t] == lj);
                    hpg[s][t] = fmaxf(hpg[s][t], same ? gg : -INFINITY);
                    hng[s][t] = fminf(hng[s][t], same ? INFINITY : gg);
                }
        }
    }

    // reduce over the 16 column-lanes sharing each output row
#pragma unroll
    for (int off = 1; off < 16; off <<= 1)
#pragma unroll
        for (int s = 0; s < 4; ++s)
#pragma unroll
            for (int t = 0; t < 4; ++t) {
                hpg[s][t] = fmaxf(hpg[s][t], __shfl_xor(hpg[s][t], off, 64));
                hng[s][t] = fminf(hng[s][t], __shfl_xor(hng[s][t], off, 64));
            }
    if (lrow == 0) {
#pragma unroll
        for (int s = 0; s < 4; ++s)
#pragma unroll
            for (int t = 0; t < 4; ++t) {
                int i = i0 + w * 64 + s * 16 + lk * 4 + t;
                atomicMax(&hpK[i], fkey(hpg[s][t]));   // order-independent => deterministic
                atomicMin(&hnK[i], fkey(hng[s][t]));
            }
    }

    // ---- ticket: last block to finish performs the finalize ----
    __threadfence();                       // make this block's atomics visible
    __shared__ unsigned lastBlk;
    if (tid == 0)
        lastBlk = (atomicAdd(ticket, 1u) == NBLKS - 1) ? 1u : 0u;
    __syncthreads();
    if (!lastBlk) return;

    // finalize (one block, 256 threads, fixed order => deterministic).
    // idempotent atomics read the final keys coherently across XCDs.
    float total = 0.f, cntv = 0.f;
#pragma unroll 1
    for (int k = 0; k < NN / 256; ++k) {
        int i = tid + k * 256;
        unsigned hk = atomicMax(&hpK[i], 0x007FFFFFu);   // returns current max
        unsigned nk = atomicMin(&hnK[i], 0xFF800000u);   // returns current min
        float hp = fkey_inv(hk);
        float hn = fkey_inv(nk);
        float s  = sjc[i].x;
        float hp2 = s + hp, hn2 = s + hn;                 // d^2 = sq_i + g
        float hpd = (hp2 == -INFINITY) ? -INFINITY : sqrtf(fmaxf(hp2, 0.f));
        float hnd = (hn2 ==  INFINITY) ?  INFINITY : sqrtf(fmaxf(hn2, 0.f));
        float tl = hpd - hnd + 1.0f;                      // -inf propagates, no NaN
        if (tl > 0.f) { total += tl; cntv += 1.f; }
    }
#pragma unroll
    for (int off = 1; off < 64; off <<= 1) {
        total += __shfl_xor(total, off, 64);
        cntv  += __shfl_xor(cntv,  off, 64);
    }
    __shared__ float sT[4], sC[4];
    if ((tid & 63) == 0) { sT[tid >> 6] = total; sC[tid >> 6] = cntv; }
    __syncthreads();
    if (tid == 0) {
        float T  = sT[0] + sT[1] + sT[2] + sT[3];
        float Cn = sC[0] + sC[1] + sC[2] + sC[3];
        out[0] = (Cn > 0.f) ? T / Cn : 0.f;
    }
}

extern "C" void kernel_launch(void* const* d_in, const int* in_sizes, int n_in,
                              void* d_out, int out_size, void* d_ws, size_t ws_size,
                              hipStream_t stream) {
    const float* emb = (const float*)d_in[0];
    const int*   lab = (const int*)d_in[1];
    char* ws = (char*)d_ws;
    float2*   sjc    = (float2*)(ws + WS_SJC);
    unsigned* hpK    = (unsigned*)(ws + WS_HPK);
    unsigned* hnK    = (unsigned*)(ws + WS_HNK);
    unsigned* ticket = (unsigned*)(ws + WS_CNT);
    ushort*   aB     = (ushort*)(ws + WS_AB);

    prepq_k<<<dim3(NN / 8), dim3(256), 0, stream>>>(emb, lab, sjc, hpK, hnK, ticket, aB);
    hardest_k<<<dim3(NBLKS), dim3(256), 0, stream>>>(aB, sjc, hpK, hnK, ticket, (float*)d_out);
}

// Round 21
// 39.115 us; speedup vs baseline: 1.8686x; 1.8686x over previous
//
#include <hip/hip_runtime.h>
#include <hip/hip_bf16.h>
#include <math.h>

#define NN 8192
#define DD 128
#define BM 256        // rows per block (4 waves x 64)
#define BN 64         // cols per j-tile
#define NPART 16      // grid = 32*16 = 512 blocks (2 blocks/CU, single batch)
#define JRANGE (NN / NPART)    // 512
#define NTILES (JRANGE / BN)   // 8

typedef __attribute__((ext_vector_type(8))) short bf16x8;
typedef __attribute__((ext_vector_type(4))) float f32x4;

// ws byte offsets
#define WS_SJC 0                          // 8192 * float2 = 64 KB
#define WS_HPK 65536                      // 32 KB (uint keys)
#define WS_HNK (WS_HPK + NN * 4)          // 32 KB
#define WS_AB  (WS_HNK + NN * 4)          // 2 MB (bf16, fragment-contiguous)

// order-preserving float -> uint key (unsigned compare == float compare)
__device__ __forceinline__ unsigned fkey(float f) {
    unsigned u = __float_as_uint(f);
    return (u & 0x80000000u) ? ~u : (u | 0x80000000u);
}
__device__ __forceinline__ float fkey_inv(unsigned k) {
    unsigned u = (k & 0x80000000u) ? (k ^ 0x80000000u) : ~k;
    return __uint_as_float(u);
}
__device__ __forceinline__ ushort f2bf(float x) {
    __hip_bfloat16 h = __float2bfloat16(x);
    return *reinterpret_cast<ushort*>(&h);
}

// fused: fp32 sqnorm + bf16 convert (fragment-contiguous) + metadata + key init
// bf16 ushort index(row,k) = (row>>4)*2048 + (k>>5)*512 + ((k>>3)&3)*128
//                          + (row&15)*8 + (k&7)
// => wave fragment (group g, kchunk q) load = &aB[g*2048 + q*512 + lane*8], 16B/lane
__global__ __launch_bounds__(256)
void prepq_k(const float* __restrict__ emb, const int* __restrict__ lab,
             float2* __restrict__ sjc, unsigned* __restrict__ hpK,
             unsigned* __restrict__ hnK, ushort* __restrict__ aB) {
    const int lane = threadIdx.x & 63;
    const int w    = threadIdx.x >> 6;
    const int half = lane >> 5;
    const int l32  = lane & 31;
    const int row  = blockIdx.x * 8 + w * 2 + half;

    float4 v = reinterpret_cast<const float4*>(emb)[row * 32 + l32];
    float s = 0.f;
    s = fmaf(v.x, v.x, s); s = fmaf(v.y, v.y, s);
    s = fmaf(v.z, v.z, s); s = fmaf(v.w, v.w, s);
#pragma unroll
    for (int off = 1; off < 32; off <<= 1) s += __shfl_xor(s, off, 64);

    ushort4 b;
    b.x = f2bf(v.x); b.y = f2bf(v.y); b.z = f2bf(v.z); b.w = f2bf(v.w);
    // k = l32*4 .. l32*4+3  ->  q = l32>>3, lk = (l32>>1)&3, e0 = (l32&1)*4
    const int idx = (row >> 4) * 2048 + (l32 >> 3) * 512 + ((l32 >> 1) & 3) * 128
                  + (row & 15) * 8 + (l32 & 1) * 4;
    *reinterpret_cast<ushort4*>(aB + idx) = b;

    if (l32 == 0) sjc[row] = make_float2(s, __int_as_float(lab[row]));
    if (threadIdx.x < 8) {
        int r0 = blockIdx.x * 8 + threadIdx.x;
        hpK[r0] = 0x007FFFFFu;   // fkey(-inf)
        hnK[r0] = 0xFF800000u;   // fkey(+inf)
    }
}

__global__ __launch_bounds__(256, 2)
void hardest_k(const ushort* __restrict__ aB, const float2* __restrict__ sjc,
               unsigned* __restrict__ hpK, unsigned* __restrict__ hnK) {
    const int tid  = threadIdx.x;
    const int w    = tid >> 6;
    const int lane = tid & 63;
    const int lrow = lane & 15;
    const int lk   = lane >> 4;
    const int ib   = (int)blockIdx.x >> 4;    // 0..31
    const int part = (int)blockIdx.x & 15;    // 0..15
    const int i0   = ib * BM;
    const int jbeg = part * JRANGE;

    // persistent A fragments: 4 strips of 16 rows x 4 k-chunks (64 VGPR)
    bf16x8 a[4][4];
#pragma unroll
    for (int s = 0; s < 4; ++s) {
        const int gA = ib * 16 + w * 4 + s;
#pragma unroll
        for (int q = 0; q < 4; ++q)
            a[s][q] = *reinterpret_cast<const bf16x8*>(&aB[gA * 2048 + q * 512 + lane * 8]);
    }
    int   li[4][4];
    float hpg[4][4], hng[4][4];
#pragma unroll
    for (int s = 0; s < 4; ++s)
#pragma unroll
        for (int t = 0; t < 4; ++t) {
            float2 md = sjc[i0 + w * 64 + s * 16 + lk * 4 + t];
            li[s][t]  = __float_as_int(md.y);
            hpg[s][t] = -INFINITY;
            hng[s][t] =  INFINITY;
        }

#pragma unroll 2
    for (int jt = 0; jt < NTILES; ++jt) {
        const int j0 = jbeg + jt * BN;
#pragma unroll
        for (int c = 0; c < 4; ++c) {
            const int gB = (j0 >> 4) + c;
            const ushort* bp = &aB[gB * 2048 + lane * 8];
            bf16x8 b0 = *reinterpret_cast<const bf16x8*>(bp);
            bf16x8 b1 = *reinterpret_cast<const bf16x8*>(bp + 512);
            bf16x8 b2 = *reinterpret_cast<const bf16x8*>(bp + 1024);
            bf16x8 b3 = *reinterpret_cast<const bf16x8*>(bp + 1536);
            float2 sv = sjc[j0 + c * 16 + lrow];
            f32x4 acc[4];
            f32x4 zero = {0.f, 0.f, 0.f, 0.f};
#pragma unroll
            for (int s = 0; s < 4; ++s) acc[s] = zero;
            __builtin_amdgcn_s_setprio(1);
#pragma unroll
            for (int s = 0; s < 4; ++s) {
                acc[s] = __builtin_amdgcn_mfma_f32_16x16x32_bf16(a[s][0], b0, acc[s], 0, 0, 0);
                acc[s] = __builtin_amdgcn_mfma_f32_16x16x32_bf16(a[s][1], b1, acc[s], 0, 0, 0);
                acc[s] = __builtin_amdgcn_mfma_f32_16x16x32_bf16(a[s][2], b2, acc[s], 0, 0, 0);
                acc[s] = __builtin_amdgcn_mfma_f32_16x16x32_bf16(a[s][3], b3, acc[s], 0, 0, 0);
            }
            __builtin_amdgcn_s_setprio(0);
            const float sqj = sv.x;
            const int   lj  = __float_as_int(sv.y);
#pragma unroll
            for (int s = 0; s < 4; ++s)
#pragma unroll
                for (int t = 0; t < 4; ++t) {
                    float gg = fmaf(-2.f, acc[s][t], sqj);        // g = sqj - 2*dot
                    bool same = (li[s][t] == lj);
                    hpg[s][t] = fmaxf(hpg[s][t], same ? gg : -INFINITY);
                    hng[s][t] = fminf(hng[s][t], same ? INFINITY : gg);
                }
        }
    }

    // reduce over the 16 column-lanes sharing each output row
#pragma unroll
    for (int off = 1; off < 16; off <<= 1)
#pragma unroll
        for (int s = 0; s < 4; ++s)
#pragma unroll
            for (int t = 0; t < 4; ++t) {
                hpg[s][t] = fmaxf(hpg[s][t], __shfl_xor(hpg[s][t], off, 64));
                hng[s][t] = fminf(hng[s][t], __shfl_xor(hng[s][t], off, 64));
            }
    if (lrow == 0) {
#pragma unroll
        for (int s = 0; s < 4; ++s)
#pragma unroll
            for (int t = 0; t < 4; ++t) {
                int i = i0 + w * 64 + s * 16 + lk * 4 + t;
                atomicMax(&hpK[i], fkey(hpg[s][t]));   // order-independent => deterministic
                atomicMin(&hnK[i], fkey(hng[s][t]));
            }
    }
}

__global__ __launch_bounds__(1024)
void final_k(const unsigned* __restrict__ hpK, const unsigned* __restrict__ hnK,
             const float2* __restrict__ sjc, float* __restrict__ out) {
    float total = 0.f, cnt = 0.f;
    for (int i = threadIdx.x; i < NN; i += 1024) {
        float hp = fkey_inv(hpK[i]);
        float hn = fkey_inv(hnK[i]);
        float s  = sjc[i].x;
        float hp2 = s + hp, hn2 = s + hn;                 // d^2 = sq_i + g
        float hpd = (hp2 == -INFINITY) ? -INFINITY : sqrtf(fmaxf(hp2, 0.f));
        float hnd = (hn2 ==  INFINITY) ?  INFINITY : sqrtf(fmaxf(hn2, 0.f));
        float tl = hpd - hnd + 1.0f;                      // -inf propagates, no NaN
        if (tl > 0.f) { total += tl; cnt += 1.f; }
    }
#pragma unroll
    for (int off = 1; off < 64; off <<= 1) {
        total += __shfl_xor(total, off, 64);
        cnt   += __shfl_xor(cnt,   off, 64);
    }
    __shared__ float sT[16], sC[16];
    int wave = threadIdx.x >> 6;
    if ((threadIdx.x & 63) == 0) { sT[wave] = total; sC[wave] = cnt; }
    __syncthreads();
    if (threadIdx.x == 0) {
        float T = 0.f, Cn = 0.f;
#pragma unroll
        for (int k = 0; k < 16; ++k) { T += sT[k]; Cn += sC[k]; }
        out[0] = (Cn > 0.f) ? T / Cn : 0.f;
    }
}

extern "C" void kernel_launch(void* const* d_in, const int* in_sizes, int n_in,
                              void* d_out, int out_size, void* d_ws, size_t ws_size,
                              hipStream_t stream) {
    const float* emb = (const float*)d_in[0];
    const int*   lab = (const int*)d_in[1];
    char* ws = (char*)d_ws;
    float2*   sjc = (float2*)(ws + WS_SJC);
    unsigned* hpK = (unsigned*)(ws + WS_HPK);
    unsigned* hnK = (unsigned*)(ws + WS_HNK);
    ushort*   aB  = (ushort*)(ws + WS_AB);

    prepq_k<<<dim3(NN / 8), dim3(256), 0, stream>>>(emb, lab, sjc, hpK, hnK, aB);
    hardest_k<<<dim3((NN / BM) * NPART), dim3(256), 0, stream>>>(aB, sjc, hpK, hnK);
    final_k<<<dim3(1), dim3(1024), 0, stream>>>(hpK, hnK, sjc, (float*)d_out);
}